// Round 11
// baseline (53.962 us; speedup 1.0000x reference)
//
#include <hip/hip_runtime.h>
#include <stdint.h>

// Problem constants
constexpr int NA  = 10000;   // atoms
constexpr int NH  = 75;      // hidden
constexpr int NPF = 14;      // pair features
constexpr int NW  = 5625;    // 75*75
constexpr int KK  = 1125;    // 15*75 contraction (f=0..13 -> W, f=14 -> bias)
constexpr int KK2 = 1152;    // padded to 36 MFMA k-steps
constexpr int NKC = KK2 / 8; // 144 k-subtiles of 8
constexpr int TB  = NKC * 128;       // 18432 elems per 16-row block ([144][16][8])
constexpr int RBM = 626;             // M row-blocks: 625 real + 1 pad
constexpr int BPA = (NA * NH + 255) / 256;   // 2930 phaseA blocks (thread per (a,k))
constexpr int BWT = 90;              // Wt build blocks (23040 quads)
constexpr int BMZ = 18;              // M-pad zero blocks (4608 quads)

typedef _Float16 f16;
typedef __attribute__((ext_vector_type(8))) _Float16 f16x8;
typedef __attribute__((ext_vector_type(4))) float floatx4;

__device__ __forceinline__ ushort f2h_bits(float f) {
    return __builtin_bit_cast(ushort, (f16)f);       // v_cvt_f16_f32, RNE
}

// Subtiled layout: elem (row, kk) of a 16-row block lives at
//   blockbase + (kk>>3)*128 + (row&15)*8 + (kk&7)
// so an MFMA fragment (16 rows x 32 k) is 1024 contiguous bytes, lane l at l*16.

// ---------- K1: fused  phaseA (thread per (atom,k)) | Wt build | M pad zero ----------
__global__ __launch_bounds__(256) void k_main(
    const float* __restrict__ af, const float* __restrict__ pf,
    const int* __restrict__ atp, const float* __restrict__ W,
    const float* __restrict__ bias,
    ushort* __restrict__ Mt, ushort* __restrict__ Wt, int E)
{
    const int b = blockIdx.x, tid = threadIdx.x;
    if (b < BPA) {
        // ---- phase A: M[a][f*75+k] = sum_{e: col0(e)=a} pf[e,f]*af[a1(e),k] ----
        // Thread handles one (a, k): ~30 VGPR, coalesced af loads, 46 waves/CU.
        int idx = b * 256 + tid;
        if (idx >= NA * NH) return;
        int a = idx / NH;
        int k = idx - a * NH;

        // per-thread lower_bound over sorted col0 (L2-hot atp; TLP hides latency)
        int lo = 0, hi = E;
        while (lo < hi) {
            int mid = (lo + hi) >> 1;
            if (atp[2 * mid] < a) lo = mid + 1; else hi = mid;
        }

        float mac[15] = {};
        for (int e = lo; e < E; ++e) {
            int2 pr = ((const int2*)atp)[e];     // {a0, a1}
            if (pr.x != a) break;
            float av = af[pr.y * NH + k];
            const float* pfe = pf + (size_t)e * NPF;
            float p[14];
            #pragma unroll
            for (int f = 0; f < 7; ++f) {
                float2 t = *(const float2*)&pfe[2 * f];
                p[2 * f] = t.x; p[2 * f + 1] = t.y;
            }
            #pragma unroll
            for (int f = 0; f < 14; ++f) mac[f] += p[f] * av;
            mac[14] += av;                       // bias slot (pf == 1)
        }

        ushort* mr = Mt + (size_t)(a >> 4) * TB + (a & 15) * 8;
        #pragma unroll
        for (int f = 0; f < 15; ++f) {
            int kk = f * NH + k;
            mr[(kk >> 3) * 128 + (kk & 7)] = f2h_bits(mac[f]);
        }
        if (k < KK2 - KK) {                      // 27 pad cols per row
            int kk = KK + k;
            mr[(kk >> 3) * 128 + (kk & 7)] = 0;
        }
    } else if (b < BPA + BWT) {
        // ---- Wt[hb][kc][16][8]: (h, kk) with kk = f*75+k ----
        int idx = (b - BPA) * 256 + tid;         // quad index
        if (idx >= 5 * TB / 4) return;
        int o  = idx * 4;
        int k3 = o & 7;                          // 0 or 4
        int hr = (o >> 3) & 15;
        int t  = o >> 7;
        int kc = t % NKC, hb = t / NKC;
        int h  = hb * 16 + hr;
        ushort4 st = {0, 0, 0, 0};
        if (h < NH) {
            float v[4] = {0.f, 0.f, 0.f, 0.f};
            #pragma unroll
            for (int j = 0; j < 4; ++j) {
                int kk = kc * 8 + k3 + j;
                if (kk < KK) {
                    int f = kk / 75, k = kk - f * 75;
                    v[j] = (f < NPF) ? W[f * NW + h * 75 + k] : bias[h * 75 + k];
                }
            }
            st.x = f2h_bits(v[0]); st.y = f2h_bits(v[1]);
            st.z = f2h_bits(v[2]); st.w = f2h_bits(v[3]);
        }
        ((ushort4*)Wt)[idx] = st;
    } else {
        // ---- zero M pad row-block 625 (rows 10000..10015) ----
        int idx = (b - BPA - BWT) * 256 + tid;
        if (idx < TB / 4) {
            ushort4 z = {0, 0, 0, 0};
            ((ushort4*)(Mt + (size_t)625 * TB))[idx] = z;
        }
    }
}

// ---------- K2: out[a][h] = sum_kk M[a][kk]*Wt[h][kk]  (MFMA, split-K) ----------
// Block = 4 waves over 32 M-rows; wave w does k-steps [9w, 9w+9); LDS reduce.
// All fragment loads are 1024B-contiguous (subtiled layout) -> fully coalesced.
__global__ __launch_bounds__(256) void k_gemm2(
    const ushort* __restrict__ Mt, const ushort* __restrict__ Wt,
    float* __restrict__ out)
{
    __shared__ float red[4][64][42];             // 43008 B

    const int l = threadIdx.x & 63, w = threadIdx.x >> 6;
    const int rb = blockIdx.x * 32;              // rows rb..rb+31 (313 blocks -> 10016)
    const int hi = l >> 4;

    const size_t mb0 = (size_t)(rb >> 4) * TB + l * 8;
    const size_t mb1 = mb0 + TB;

    floatx4 acc[2][5] = {};
    #pragma unroll 3
    for (int s = 0; s < 9; ++s) {
        const int ks = w * 9 + s;
        f16x8 m0 = *(const f16x8*)&Mt[mb0 + ks * 512];
        f16x8 m1 = *(const f16x8*)&Mt[mb1 + ks * 512];
        #pragma unroll
        for (int nf = 0; nf < 5; ++nf) {
            f16x8 wf = *(const f16x8*)&Wt[(size_t)nf * TB + ks * 512 + l * 8];
            acc[0][nf] = __builtin_amdgcn_mfma_f32_16x16x32_f16(wf, m0, acc[0][nf], 0, 0, 0);
            acc[1][nf] = __builtin_amdgcn_mfma_f32_16x16x32_f16(wf, m1, acc[1][nf], 0, 0, 0);
        }
    }

    // stash partials
    #pragma unroll
    for (int m = 0; m < 2; ++m)
        #pragma unroll
        for (int nf = 0; nf < 5; ++nf)
            #pragma unroll
            for (int r = 0; r < 4; ++r)
                red[w][l][m * 20 + nf * 4 + r] = acc[m][nf][r];
    __syncthreads();

    // wave w reduces j in [10w, 10w+10) across the 4 k-partials and stores
    #pragma unroll
    for (int jj = 0; jj < 10; ++jj) {
        int j = w * 10 + jj;
        float s = red[0][l][j] + red[1][l][j] + red[2][l][j] + red[3][l][j];
        int m   = j / 20;
        int rem = j - m * 20;
        int nf  = rem >> 2, r = rem & 3;
        int row = rb + m * 16 + (l & 15);
        int h   = nf * 16 + hi * 4 + r;
        if (row < NA && h < NH)
            out[(size_t)row * NH + h] = s;
    }
}

// ---------- Fallback: direct per-(edge,h) with atomics (fp32) ----------
__global__ void k_naive(const float* __restrict__ pf, const float* __restrict__ af,
                        const int* __restrict__ atp, const float* __restrict__ W,
                        const float* __restrict__ bias, float* __restrict__ out, int E)
{
    int idx = blockIdx.x * blockDim.x + threadIdx.x;
    if (idx >= E * NH) return;
    int e = idx / NH, h = idx - e * NH;
    int a0 = atp[2 * e], a1 = atp[2 * e + 1];
    float p[NPF];
    #pragma unroll
    for (int f = 0; f < NPF; ++f) p[f] = pf[(size_t)e * NPF + f];
    float acc = 0.f;
    for (int k = 0; k < NH; ++k) {
        float w = bias[h * NH + k];
        #pragma unroll
        for (int f = 0; f < NPF; ++f) w += p[f] * W[f * NW + h * NH + k];
        acc += w * af[a1 * NH + k];
    }
    atomicAdd(&out[a0 * NH + h], acc);
}

extern "C" void kernel_launch(void* const* d_in, const int* in_sizes, int n_in,
                              void* d_out, int out_size, void* d_ws, size_t ws_size,
                              hipStream_t stream) {
    const float* pf   = (const float*)d_in[0];
    const float* af   = (const float*)d_in[1];
    const int*   atp  = (const int*)d_in[2];
    const float* W    = (const float*)d_in[3];
    const float* bias = (const float*)d_in[4];
    float* out = (float*)d_out;
    const int E = in_sizes[2] / 2;

    const size_t offWt = 0;
    const size_t offMt = offWt + (size_t)5 * TB * 2;           // 184,320
    const size_t need  = offMt + (size_t)RBM * TB * 2;         // +23,076,864

    if (ws_size >= need) {
        ushort* Wt = (ushort*)((char*)d_ws + offWt);
        ushort* Mt = (ushort*)((char*)d_ws + offMt);

        k_main<<<BPA + BWT + BMZ, 256, 0, stream>>>(af, pf, atp, W, bias, Mt, Wt, E);
        k_gemm2<<<313, 256, 0, stream>>>(Mt, Wt, out);         // 313*32 = 10016 rows
    } else {
        hipMemsetAsync(d_out, 0, (size_t)out_size * sizeof(float), stream);
        k_naive<<<((size_t)E * NH + 255) / 256, 256, 0, stream>>>(pf, af, atp, W, bias, out, E);
    }
}

// Round 12
// 41.730 us; speedup vs baseline: 1.2931x; 1.2931x over previous
//
#include <hip/hip_runtime.h>
#include <stdint.h>

// Problem constants
constexpr int NA   = 10000;  // atoms
constexpr int NH   = 75;     // hidden
constexpr int NPF  = 14;     // pair features
constexpr int NW   = 5625;   // 75*75
constexpr int NCOL = 1200;   // 75*16: per h -> f=0..13 W-cols, f=14 bias, f=15 pad
constexpr int KP   = 104;    // K padded: 75 data, zeros to 96 (3 MFMA k-steps)
constexpr int WIN  = 16;     // a1 atoms per window block; NA/WIN = 625
constexpr int USTR = 1208;   // U_lds row stride in ushorts (1200 + 8 pad)

typedef _Float16 f16;
typedef __attribute__((ext_vector_type(2))) _Float16 f16x2;
typedef __attribute__((ext_vector_type(8))) _Float16 f16x8;
typedef __attribute__((ext_vector_type(4))) float floatx4;

__device__ __forceinline__ ushort f2h_bits(float f) {
    return __builtin_bit_cast(ushort, (f16)f);       // v_cvt_f16_f32, RNE
}
__device__ __forceinline__ f16x2 bch(uint32_t w) {
    return __builtin_bit_cast(f16x2, w);
}
__device__ __forceinline__ uint32_t pk2(float a, float b) {
    return __builtin_bit_cast(uint32_t, __builtin_amdgcn_cvt_pkrtz(a, b));
}

// 16-wide f16 dot via 8x v_dot2_f32_f16 (f32 accumulate)
__device__ __forceinline__ float dot16(uint4 p0, uint4 p1, uint4 u0, uint4 u1) {
    float c = 0.f;
    c = __builtin_amdgcn_fdot2(bch(p0.x), bch(u0.x), c, false);
    c = __builtin_amdgcn_fdot2(bch(p0.y), bch(u0.y), c, false);
    c = __builtin_amdgcn_fdot2(bch(p0.z), bch(u0.z), c, false);
    c = __builtin_amdgcn_fdot2(bch(p0.w), bch(u0.w), c, false);
    c = __builtin_amdgcn_fdot2(bch(p1.x), bch(u1.x), c, false);
    c = __builtin_amdgcn_fdot2(bch(p1.y), bch(u1.y), c, false);
    c = __builtin_amdgcn_fdot2(bch(p1.z), bch(u1.z), c, false);
    c = __builtin_amdgcn_fdot2(bch(p1.w), bch(u1.w), c, false);
    return c;
}

// ---------- K1: prep = cvt_af | cvt_w | (cvt_pf + rs0 + rs1) ----------
__global__ __launch_bounds__(256) void k_prep(
    const float* __restrict__ af, const float* __restrict__ W,
    const float* __restrict__ bias, const float* __restrict__ pf,
    const int* __restrict__ atp,
    ushort* __restrict__ afb, ushort* __restrict__ wbt,
    ushort* __restrict__ pfh, int* __restrict__ rs0, int* __restrict__ rs1,
    int E, int bA, int bW)
{
    const int b = blockIdx.x, tid = threadIdx.x;
    if (b < bA) {
        // af -> f16 [NA][KP], zero padded
        int idx = b * 256 + tid;
        if (idx >= NA * (KP / 4)) return;
        int a = idx / (KP / 4), q = idx - a * (KP / 4);
        int k0 = q * 4;
        float v[4];
        #pragma unroll
        for (int j = 0; j < 4; ++j) {
            int k = k0 + j;
            v[j] = (k < NH) ? af[a * NH + k] : 0.f;
        }
        ushort4 st;
        st.x = f2h_bits(v[0]); st.y = f2h_bits(v[1]);
        st.z = f2h_bits(v[2]); st.w = f2h_bits(v[3]);
        ((ushort4*)afb)[idx] = st;
    } else if (b < bA + bW) {
        // Wbt[c][k] f16, c = h*16+f (N-major)
        int idx = (b - bA) * 256 + tid;
        if (idx >= NCOL * (KP / 4)) return;
        int c = idx / (KP / 4), q = idx - c * (KP / 4);
        int k0 = q * 4;
        int h = c >> 4, f = c & 15;
        float v[4] = {0.f, 0.f, 0.f, 0.f};
        #pragma unroll
        for (int j = 0; j < 4; ++j) {
            int k = k0 + j;
            if (k < NH) {
                if (f < NPF)       v[j] = W[f * NW + h * NH + k];
                else if (f == NPF) v[j] = bias[h * NH + k];
            }
        }
        ushort4 st;
        st.x = f2h_bits(v[0]); st.y = f2h_bits(v[1]);
        st.z = f2h_bits(v[2]); st.w = f2h_bits(v[3]);
        ((ushort4*)wbt)[idx] = st;
    } else {
        // per-edge: pf -> f16x16 (slot14=1.0 bias, slot15=0) + rs0 + rs1 CSR
        int e = (b - bA - bW) * 256 + tid;
        if (e >= E) return;
        const float* pfe = pf + (size_t)e * NPF;
        union { f16 h[16]; uint4 q[2]; } u;
        #pragma unroll
        for (int f = 0; f < 7; ++f) {
            float2 t = *(const float2*)&pfe[2 * f];
            u.h[2 * f]     = (f16)t.x;
            u.h[2 * f + 1] = (f16)t.y;
        }
        u.h[14] = (f16)1.0f;
        u.h[15] = (f16)0.0f;
        uint4* dst = (uint4*)(pfh + (size_t)e * 16);
        dst[0] = u.q[0]; dst[1] = u.q[1];

        int c0  = atp[2 * e];
        int c0p = (e == 0) ? -1 : atp[2 * (e - 1)];
        for (int a = c0p + 1; a <= c0; ++a) rs0[a] = e;
        int c1  = atp[2 * e + 1];
        int c1p = (e == 0) ? -1 : atp[2 * (e - 1) + 1];
        for (int a = c1p + 1; a <= c1; ++a) rs1[a] = e;
        if (e == E - 1) {
            for (int a = c0 + 1; a <= NA; ++a) rs0[a] = E;
            for (int a = c1 + 1; a <= NA; ++a) rs1[a] = E;
        }
    }
}

// ---------- K2: per-a1-window U in LDS (MFMA) + per-edge dots -> O ----------
// Block b owns a1 in [16b, 16b+16). Phase 1: U_lds[16][1200] = afb_win @ wbt^T
// (r5-verified). Phase 2: edges rs1[ab0]..rs1[ab0+16] (col-1 sorted ->
// contiguous), one edge/thread, 75 LDS dots -> O[h8][e][8] f16 (coalesced).
__global__ __launch_bounds__(256) void k_window(
    const ushort* __restrict__ afb, const ushort* __restrict__ wbt,
    const ushort* __restrict__ pfh, const int* __restrict__ atp,
    const int* __restrict__ rs1, ushort* __restrict__ O, int E)
{
    __shared__ __align__(16) ushort U[WIN * USTR];   // 38656 B

    const int tid  = threadIdx.x;
    const int lane = tid & 63, wid = tid >> 6;
    const int ab0  = blockIdx.x * WIN;

    const int lr  = lane & 15;           // a-row within window / D col
    const int lko = (lane >> 4) * 8;     // k elem offset within 32-chunk

    f16x8 a[3];
    #pragma unroll
    for (int ks = 0; ks < 3; ++ks)
        a[ks] = *(const f16x8*)&afb[(size_t)(ab0 + lr) * KP + ks * 32 + lko];

    for (int i = 0; i < 19; ++i) {
        int nf = wid + 4 * i;
        if (nf < 75) {
            floatx4 acc = {};
            #pragma unroll
            for (int ks = 0; ks < 3; ++ks) {
                f16x8 bfr = *(const f16x8*)&wbt[(size_t)(nf * 16 + lr) * KP + ks * 32 + lko];
                acc = __builtin_amdgcn_mfma_f32_16x16x32_f16(bfr, a[ks], acc, 0, 0, 0);
            }
            int cbase = nf * 16 + (lane >> 4) * 4;
            uint2 st;
            st.x = pk2(acc[0], acc[1]);
            st.y = pk2(acc[2], acc[3]);
            *(uint2*)&U[lr * USTR + cbase] = st;
        }
    }
    __syncthreads();

    const int e0 = rs1[ab0], e1 = rs1[ab0 + WIN];
    for (int e = e0 + tid; e < e1; e += 256) {
        int la1 = atp[2 * e + 1] - ab0;
        const uint4* pq = (const uint4*)(pfh + (size_t)e * 16);
        uint4 p0 = pq[0], p1 = pq[1];
        const ushort* ur = U + la1 * USTR;
        #pragma unroll
        for (int h8 = 0; h8 < 10; ++h8) {
            float s[8];
            #pragma unroll
            for (int j = 0; j < 8; ++j) {
                int h = h8 * 8 + j;
                if (h < NH) {
                    const uint4* up = (const uint4*)(ur + h * 16);
                    s[j] = dot16(p0, p1, up[0], up[1]);
                } else s[j] = 0.f;
            }
            uint4 st;
            st.x = pk2(s[0], s[1]); st.y = pk2(s[2], s[3]);
            st.z = pk2(s[4], s[5]); st.w = pk2(s[6], s[7]);
            *(uint4*)(O + (size_t)(h8 * E + e) * 8) = st;   // coalesced across lanes
        }
    }
}

// ---------- K3: out[a][h] = sum_{e in rs0[a]} O[h8][e][j]  (no atomics) ----------
__global__ __launch_bounds__(256) void k_sum(
    const ushort* __restrict__ O, const int* __restrict__ rs0,
    float* __restrict__ out, int E)
{
    int idx = blockIdx.x * blockDim.x + threadIdx.x;
    if (idx >= NA * 10) return;
    int oct = idx / NA;                  // h-octet 0..9
    int a   = idx - oct * NA;            // lanes -> consecutive atoms
    int e0 = rs0[a], e1 = rs0[a + 1];

    float s[8] = {};
    for (int e = e0; e < e1; ++e) {
        uint4 v = *(const uint4*)(O + (size_t)(oct * E + e) * 8);
        f16x2 t;
        t = bch(v.x); s[0] += (float)t[0]; s[1] += (float)t[1];
        t = bch(v.y); s[2] += (float)t[0]; s[3] += (float)t[1];
        t = bch(v.z); s[4] += (float)t[0]; s[5] += (float)t[1];
        t = bch(v.w); s[6] += (float)t[0]; s[7] += (float)t[1];
    }
    #pragma unroll
    for (int j = 0; j < 8; ++j) {
        int h = oct * 8 + j;
        if (h < NH) out[(size_t)a * NH + h] = s[j];
    }
}

// ---------- Fallback: direct per-(edge,h) with atomics (fp32) ----------
__global__ void k_naive(const float* __restrict__ pf, const float* __restrict__ af,
                        const int* __restrict__ atp, const float* __restrict__ W,
                        const float* __restrict__ bias, float* __restrict__ out, int E)
{
    int idx = blockIdx.x * blockDim.x + threadIdx.x;
    if (idx >= E * NH) return;
    int e = idx / NH, h = idx - e * NH;
    int a0 = atp[2 * e], a1 = atp[2 * e + 1];
    float p[NPF];
    #pragma unroll
    for (int f = 0; f < NPF; ++f) p[f] = pf[(size_t)e * NPF + f];
    float acc = 0.f;
    for (int k = 0; k < NH; ++k) {
        float w = bias[h * NH + k];
        #pragma unroll
        for (int f = 0; f < NPF; ++f) w += p[f] * W[f * NW + h * NH + k];
        acc += w * af[a1 * NH + k];
    }
    atomicAdd(&out[a0 * NH + h], acc);
}

extern "C" void kernel_launch(void* const* d_in, const int* in_sizes, int n_in,
                              void* d_out, int out_size, void* d_ws, size_t ws_size,
                              hipStream_t stream) {
    const float* pf   = (const float*)d_in[0];
    const float* af   = (const float*)d_in[1];
    const int*   atp  = (const int*)d_in[2];
    const float* W    = (const float*)d_in[3];
    const float* bias = (const float*)d_in[4];
    float* out = (float*)d_out;
    const int E = in_sizes[2] / 2;

    const size_t offAfb = 0;
    const size_t offWbt = offAfb + (size_t)NA * KP * 2;        // 2,080,000
    const size_t offPfh = offWbt + (size_t)NCOL * KP * 2;      // +249,600
    const size_t offO   = offPfh + (size_t)E * 16 * 2;         // +2,048,000
    const size_t offRs0 = offO + (size_t)E * 80 * 2;           // +10,240,000
    const size_t offRs1 = offRs0 + (size_t)(NA + 1) * sizeof(int);
    const size_t need   = offRs1 + (size_t)(NA + 1) * sizeof(int);

    if (ws_size >= need) {
        ushort* afb = (ushort*)((char*)d_ws + offAfb);
        ushort* wbt = (ushort*)((char*)d_ws + offWbt);
        ushort* pfh = (ushort*)((char*)d_ws + offPfh);
        ushort* O   = (ushort*)((char*)d_ws + offO);
        int*    rs0 = (int*)((char*)d_ws + offRs0);
        int*    rs1 = (int*)((char*)d_ws + offRs1);

        const int bA = (NA * (KP / 4) + 255) / 256;     // 1016
        const int bW = (NCOL * (KP / 4) + 255) / 256;   // 122
        const int bP = (E + 255) / 256;                 // 250
        k_prep<<<bA + bW + bP, 256, 0, stream>>>(af, W, bias, pf, atp,
                                                 afb, wbt, pfh, rs0, rs1, E, bA, bW);

        k_window<<<NA / WIN, 256, 0, stream>>>(afb, wbt, pfh, atp, rs1, O, E);

        k_sum<<<(NA * 10 + 255) / 256, 256, 0, stream>>>(O, rs0, out, E);
    } else {
        hipMemsetAsync(d_out, 0, (size_t)out_size * sizeof(float), stream);
        k_naive<<<((size_t)E * NH + 255) / 256, 256, 0, stream>>>(pf, af, atp, W, bias, out, E);
    }
}

// Round 13
// 36.925 us; speedup vs baseline: 1.4614x; 1.1301x over previous
//
#include <hip/hip_runtime.h>
#include <hip/hip_bf16.h>
#include <stdint.h>

// Problem constants
constexpr int NA   = 10000;  // atoms
constexpr int NH   = 75;     // hidden
constexpr int NPF  = 14;     // pair features
constexpr int NW   = 5625;   // 75*75
constexpr int NCOL = 1200;   // 75*16: per h -> f=0..13 W-cols, f=14 bias, f=15 pad
constexpr int KP   = 104;    // K padded: 75 data, zeros to 96 (3 MFMA k-steps)
constexpr int MROW = 10112;  // NA padded to 79*128
constexpr int WROW = 1208;   // NCOL padded rows for staging slack
constexpr int BN   = 240;    // gemm col-tile (15 n-frags), NCOL/BN = 5
constexpr int ACH  = 26;     // A staging chunks of 1024B (128*104*2 = 26624B)
constexpr int BCH  = 49;     // B staging chunks (240*104*2 = 49920B)
constexpr int EWIN = 16;     // atoms per edge-window block; NA/EWIN = 625
constexpr int ECH  = 128;    // staged edges per chunk

typedef _Float16 f16;
typedef __attribute__((ext_vector_type(2))) _Float16 f16x2;
typedef __attribute__((ext_vector_type(8))) _Float16 f16x8;
typedef __attribute__((ext_vector_type(4))) float floatx4;

__device__ __forceinline__ ushort f2h_bits(float f) {
    return __builtin_bit_cast(ushort, (f16)f);       // v_cvt_f16_f32, RNE
}
__device__ __forceinline__ f16x2 bch(uint32_t w) {
    return __builtin_bit_cast(f16x2, w);
}

__device__ __forceinline__ void gload16(const void* g, void* l) {
    __builtin_amdgcn_global_load_lds(
        (const __attribute__((address_space(1))) uint32_t*)g,
        (__attribute__((address_space(3))) uint32_t*)l, 16, 0, 0);
}

// bijective XCD chunk swizzle (m204)
__device__ __forceinline__ int xcd_swz(int orig, int nwg) {
    int q = nwg >> 3, r = nwg & 7;
    int xcd = orig & 7, i = orig >> 3;
    return (xcd < r ? xcd * (q + 1) : r * (q + 1) + (xcd - r) * q) + i;
}

// 16-wide f16 dot via 8x v_dot2_f32_f16 (f32 accumulate)
__device__ __forceinline__ float dot16(uint4 p0, uint4 p1, uint4 u0, uint4 u1, float c) {
    c = __builtin_amdgcn_fdot2(bch(p0.x), bch(u0.x), c, false);
    c = __builtin_amdgcn_fdot2(bch(p0.y), bch(u0.y), c, false);
    c = __builtin_amdgcn_fdot2(bch(p0.z), bch(u0.z), c, false);
    c = __builtin_amdgcn_fdot2(bch(p0.w), bch(u0.w), c, false);
    c = __builtin_amdgcn_fdot2(bch(p1.x), bch(u1.x), c, false);
    c = __builtin_amdgcn_fdot2(bch(p1.y), bch(u1.y), c, false);
    c = __builtin_amdgcn_fdot2(bch(p1.z), bch(u1.z), c, false);
    c = __builtin_amdgcn_fdot2(bch(p1.w), bch(u1.w), c, false);
    return c;
}

// ---------- K1: fused prep: cvt_af | cvt_w | cvt_pf | rowstart(a0) ----------
__global__ __launch_bounds__(256) void k_prep(
    const float* __restrict__ af, const float* __restrict__ W,
    const float* __restrict__ bias, const float* __restrict__ pf,
    const int* __restrict__ atp,
    ushort* __restrict__ afb, ushort* __restrict__ wbt,
    ushort* __restrict__ pfh, int* __restrict__ rs,
    int E, int bA, int bW, int bP)
{
    const int b = blockIdx.x, tid = threadIdx.x;
    if (b < bA) {
        int idx = b * 256 + tid;
        if (idx >= MROW * (KP / 4)) return;
        int a = idx / (KP / 4), q = idx - a * (KP / 4);
        int k0 = q * 4;
        ushort4 st = {0, 0, 0, 0};
        if (a < NA) {
            float v[4];
            #pragma unroll
            for (int j = 0; j < 4; ++j) {
                int k = k0 + j;
                v[j] = (k < NH) ? af[a * NH + k] : 0.f;
            }
            st.x = f2h_bits(v[0]); st.y = f2h_bits(v[1]);
            st.z = f2h_bits(v[2]); st.w = f2h_bits(v[3]);
        }
        ((ushort4*)afb)[idx] = st;
    } else if (b < bA + bW) {
        int idx = (b - bA) * 256 + tid;
        if (idx >= WROW * (KP / 4)) return;
        int c = idx / (KP / 4), q = idx - c * (KP / 4);
        int k0 = q * 4;
        ushort4 st = {0, 0, 0, 0};
        if (c < NCOL) {
            int h = c >> 4, f = c & 15;
            float v[4] = {0.f, 0.f, 0.f, 0.f};
            #pragma unroll
            for (int j = 0; j < 4; ++j) {
                int k = k0 + j;
                if (k < NH) {
                    if (f < NPF)       v[j] = W[f * NW + h * NH + k];
                    else if (f == NPF) v[j] = bias[h * NH + k];
                }
            }
            st.x = f2h_bits(v[0]); st.y = f2h_bits(v[1]);
            st.z = f2h_bits(v[2]); st.w = f2h_bits(v[3]);
        }
        ((ushort4*)wbt)[idx] = st;
    } else if (b < bA + bW + bP) {
        // pf -> f16x16 per edge, slot14 = 1.0 (bias), slot15 = 0
        int e = (b - bA - bW) * 256 + tid;
        if (e >= E) return;
        const float* pfe = pf + (size_t)e * NPF;
        union { f16 h[16]; uint4 q[2]; } u;
        #pragma unroll
        for (int f = 0; f < 7; ++f) {
            float2 t = *(const float2*)&pfe[2 * f];
            u.h[2 * f]     = (f16)t.x;
            u.h[2 * f + 1] = (f16)t.y;
        }
        u.h[14] = (f16)1.0f;
        u.h[15] = (f16)0.0f;
        uint4* dst = (uint4*)(pfh + (size_t)e * 16);
        dst[0] = u.q[0]; dst[1] = u.q[1];
    } else {
        // rowstart CSR from sorted atom_to_pair[:,0]
        int e = (b - bA - bW - bP) * 256 + tid;
        if (e >= E) return;
        int c  = atp[2 * e];
        int cp = (e == 0) ? -1 : atp[2 * (e - 1)];
        for (int a = cp + 1; a <= c; ++a) rs[a] = e;
        if (e == E - 1)
            for (int a = c + 1; a <= NA; ++a) rs[a] = E;
    }
}

// ---------- K2: MFMA GEMM  U[a][c] = sum_k afb[a][k]*Wbt[c][k] (r6-identical) ----------
__global__ __launch_bounds__(256, 2) void k_gemm(const ushort* __restrict__ afb,
                                                 const ushort* __restrict__ wbt,
                                                 ushort* __restrict__ U) {
    __shared__ __align__(16) ushort sm[38400];
    ushort* As = sm;                                   // [128][104]
    ushort* Bs = sm + 13312;                           // [~241][104]

    const int nwg = (NCOL / BN) * (MROW / 128);        // 395
    const int swz = xcd_swz(blockIdx.x, nwg);
    const int by  = swz / (NCOL / BN);
    const int bx  = swz - by * (NCOL / BN);

    const int tid  = threadIdx.x;
    const int lane = tid & 63, wid = tid >> 6;
    const int a0 = by * 128;
    const int c0 = bx * BN;

    const char* aSrc = (const char*)(afb + (size_t)a0 * KP);
    const char* bSrc = (const char*)(wbt + (size_t)c0 * KP);

    for (int c = wid; c < ACH + BCH; c += 4) {
        if (c < ACH) gload16(aSrc + c * 1024 + lane * 16, (char*)As + c * 1024);
        else {
            int cb = c - ACH;
            gload16(bSrc + cb * 1024 + lane * 16, (char*)Bs + cb * 1024);
        }
    }
    __syncthreads();

    const int lr = lane & 15;
    const int lk = (lane >> 4) * 8;
    floatx4 acc[15][2] = {};

    #pragma unroll
    for (int ks = 0; ks < 3; ++ks) {
        f16x8 a[2], bv[15];
        #pragma unroll
        for (int mf = 0; mf < 2; ++mf)
            a[mf] = *(const f16x8*)&As[(wid * 32 + mf * 16 + lr) * KP + ks * 32 + lk];
        #pragma unroll
        for (int nf = 0; nf < 15; ++nf)
            bv[nf] = *(const f16x8*)&Bs[(nf * 16 + lr) * KP + ks * 32 + lk];
        #pragma unroll
        for (int nf = 0; nf < 15; ++nf)
            #pragma unroll
            for (int mf = 0; mf < 2; ++mf)
                acc[nf][mf] = __builtin_amdgcn_mfma_f32_16x16x32_f16(
                    bv[nf], a[mf], acc[nf][mf], 0, 0, 0);
    }

    #pragma unroll
    for (int mf = 0; mf < 2; ++mf) {
        int arow = a0 + wid * 32 + mf * 16 + lr;
        if (arow >= NA) continue;
        #pragma unroll
        for (int nf = 0; nf < 15; ++nf) {
            int cbase = c0 + nf * 16 + (lane >> 4) * 4;
            uint2 st;
            st.x = __builtin_bit_cast(uint32_t,
                     __builtin_amdgcn_cvt_pkrtz(acc[nf][mf][0], acc[nf][mf][1]));
            st.y = __builtin_bit_cast(uint32_t,
                     __builtin_amdgcn_cvt_pkrtz(acc[nf][mf][2], acc[nf][mf][3]));
            *(uint2*)&U[(size_t)arow * NCOL + cbase] = st;
        }
    }
}

// ---------- K3: 16-atom-window edge loop with LDS pfh dedup ----------
// Block owns atoms [ab0, ab0+16). Edges rs[ab0]..rs[ab0+16] are contiguous
// (col-0 sorted). Stage pfh+a1 for <=128 edges into LDS per chunk (coalesced),
// then thread (al, j) = (tid>>4, tid&15) accumulates h = j+16r (r<5) for its
// atom, pfh via free same-address LDS broadcast. Order per (a,h) == r6.
__global__ __launch_bounds__(256) void k_edges_win(
    const ushort* __restrict__ pfh, const int* __restrict__ atp,
    const int* __restrict__ rs, const ushort* __restrict__ U,
    float* __restrict__ out)
{
    __shared__ uint4 pfs[ECH][2];        // 4 KB
    __shared__ int   a1s[ECH];           // 512 B

    const int tid = threadIdx.x;
    const int blk = xcd_swz(blockIdx.x, NA / EWIN);    // 625 blocks
    const int ab0 = blk * EWIN;
    const int al  = tid >> 4, j = tid & 15;
    const int a   = ab0 + al;

    const int e0w = rs[ab0], e1w = rs[ab0 + EWIN];
    const int e0  = rs[a],   e1  = rs[a + 1];

    float acc[5] = {};
    for (int cs = e0w; cs < e1w; cs += ECH) {
        int n = e1w - cs; if (n > ECH) n = ECH;
        __syncthreads();                 // prior chunk's LDS reads done
        for (int i = tid; i < n * 2; i += 256)
            pfs[i >> 1][i & 1] = *(const uint4*)(pfh + (size_t)(cs + (i >> 1)) * 16 + (i & 1) * 8);
        for (int i = tid; i < n; i += 256)
            a1s[i] = atp[2 * (cs + i) + 1];
        __syncthreads();

        int lo = e0 > cs ? e0 : cs;
        int hi = e1 < cs + n ? e1 : cs + n;
        for (int e = lo; e < hi; ++e) {
            int el = e - cs;
            uint4 p0 = pfs[el][0], p1 = pfs[el][1];
            const ushort* ub = U + (size_t)a1s[el] * NCOL + j * 16;
            #pragma unroll
            for (int r = 0; r < 4; ++r) {
                const uint4* up = (const uint4*)(ub + r * 256);
                acc[r] = dot16(p0, p1, up[0], up[1], acc[r]);
            }
            if (j < NH - 64) {           // r = 4, h = j + 64 < 75
                const uint4* up = (const uint4*)(ub + 4 * 256);
                acc[4] = dot16(p0, p1, up[0], up[1], acc[4]);
            }
        }
    }

    #pragma unroll
    for (int r = 0; r < 4; ++r)
        out[(size_t)a * NH + j + 16 * r] = acc[r];
    if (j < NH - 64)
        out[(size_t)a * NH + j + 64] = acc[4];
}

// ---------- Fallback: direct per-(edge,h) with atomics (fp32) ----------
__global__ void k_naive(const float* __restrict__ pf, const float* __restrict__ af,
                        const int* __restrict__ atp, const float* __restrict__ W,
                        const float* __restrict__ bias, float* __restrict__ out, int E)
{
    int idx = blockIdx.x * blockDim.x + threadIdx.x;
    if (idx >= E * NH) return;
    int e = idx / NH, h = idx - e * NH;
    int a0 = atp[2 * e], a1 = atp[2 * e + 1];
    float p[NPF];
    #pragma unroll
    for (int f = 0; f < NPF; ++f) p[f] = pf[(size_t)e * NPF + f];
    float acc = 0.f;
    for (int k = 0; k < NH; ++k) {
        float w = bias[h * NH + k];
        #pragma unroll
        for (int f = 0; f < NPF; ++f) w += p[f] * W[f * NW + h * NH + k];
        acc += w * af[a1 * NH + k];
    }
    atomicAdd(&out[a0 * NH + h], acc);
}

extern "C" void kernel_launch(void* const* d_in, const int* in_sizes, int n_in,
                              void* d_out, int out_size, void* d_ws, size_t ws_size,
                              hipStream_t stream) {
    const float* pf   = (const float*)d_in[0];
    const float* af   = (const float*)d_in[1];
    const int*   atp  = (const int*)d_in[2];
    const float* W    = (const float*)d_in[3];
    const float* bias = (const float*)d_in[4];
    float* out = (float*)d_out;
    const int E = in_sizes[2] / 2;

    const size_t offAfb = 0;
    const size_t offWbt = offAfb + (size_t)MROW * KP * 2;
    const size_t offU   = offWbt + (size_t)WROW * KP * 2;
    const size_t offPfh = offU + (size_t)NA * NCOL * 2;
    const size_t offRs  = offPfh + (size_t)E * 16 * 2;
    const size_t need   = offRs + (size_t)(NA + 1) * sizeof(int);

    if (ws_size >= need) {
        ushort* afb = (ushort*)((char*)d_ws + offAfb);
        ushort* wbt = (ushort*)((char*)d_ws + offWbt);
        ushort* U   = (ushort*)((char*)d_ws + offU);
        ushort* pfh = (ushort*)((char*)d_ws + offPfh);
        int*    rs  = (int*)((char*)d_ws + offRs);

        const int bA = (MROW * (KP / 4) + 255) / 256;   // 1027
        const int bW = (WROW * (KP / 4) + 255) / 256;   // 123
        const int bP = (E + 255) / 256;                 // 250
        const int bR = (E + 255) / 256;                 // 250
        k_prep<<<bA + bW + bP + bR, 256, 0, stream>>>(af, W, bias, pf, atp,
                                                      afb, wbt, pfh, rs, E, bA, bW, bP);

        k_gemm<<<(NCOL / BN) * (MROW / 128), 256, 0, stream>>>(afb, wbt, U);

        k_edges_win<<<NA / EWIN, 256, 0, stream>>>(pfh, atp, rs, U, out);
    } else {
        hipMemsetAsync(d_out, 0, (size_t)out_size * sizeof(float), stream);
        k_naive<<<((size_t)E * NH + 255) / 256, 256, 0, stream>>>(pf, af, atp, W, bias, out, E);
    }
}